// Round 5
// baseline (359.576 us; speedup 1.0000x reference)
//
#include <hip/hip_runtime.h>
#include <math.h>

typedef float f32x4 __attribute__((ext_vector_type(4)));
typedef __attribute__((ext_vector_type(8))) short bf16x8;

#define DD 256
#define DH 128

// order-preserving float<->uint encoding for deterministic atomicMax
__device__ __forceinline__ unsigned enc_f32(float f) {
  unsigned u = __float_as_uint(f);
  return (u & 0x80000000u) ? ~u : (u | 0x80000000u);
}
__device__ __forceinline__ float dec_f32(unsigned u) {
  return __uint_as_float((u & 0x80000000u) ? (u ^ 0x80000000u) : ~u);
}
// fp32 -> bf16 bits, round-to-nearest-even
__device__ __forceinline__ unsigned short f2bf_rne(float f) {
  unsigned u = __float_as_uint(f);
  unsigned r = (u + 0x7fffu + ((u >> 16) & 1u)) >> 16;
  return (unsigned short)r;
}

// ---------------------------------------------------------------------------
// K0: W1 (256x128 fp32) -> MFMA B-fragment order, split bf16 hi+lo.
// w1hi[((kt*8+nt)*64+lane)*8+j] = bf16(W1[kt*32+(lane>>4)*8+j][nt*16+(lane&15)])
// Also initializes maxslot (runs before ap_mlp on the same stream).
// ---------------------------------------------------------------------------
__global__ void ap_prep(const float* __restrict__ W1,
                        unsigned short* __restrict__ w1hi,
                        unsigned short* __restrict__ w1lo,
                        unsigned* __restrict__ maxslot) {
  int t = blockIdx.x * blockDim.x + threadIdx.x;  // 0..4095
  if (t == 0) *maxslot = 0u;
  if (t >= 64 * 64) return;
  int l = t & 63;
  int tile = t >> 6;  // kt*8 + nt
  int kt = tile >> 3, nt = tile & 7;
  int kbase = kt * 32 + (l >> 4) * 8;
  int col = nt * 16 + (l & 15);
#pragma unroll
  for (int j = 0; j < 8; ++j) {
    float f = W1[(kbase + j) * DH + col];
    unsigned short h = f2bf_rne(f);
    float hf = __uint_as_float((unsigned)h << 16);
    unsigned short lb = f2bf_rne(f - hf);
    w1hi[t * 8 + j] = h;
    w1lo[t * 8 + j] = lb;
  }
}

// ---------------------------------------------------------------------------
// K1: segment boundaries (batch sorted). start[b] = first i with batch[i]>=b
// ---------------------------------------------------------------------------
__global__ void ap_bounds(const int* __restrict__ batch, int* __restrict__ start,
                          int nrows, int bseg) {
  int i = blockIdx.x * blockDim.x + threadIdx.x;
  if (i >= nrows) return;
  int c = batch[i];
  int p = (i == 0) ? -1 : batch[i - 1];
  for (int b = p + 1; b <= c; ++b) start[b] = i;
  if (i == nrows - 1) {
    for (int b = c + 1; b <= bseg; ++b) start[b] = nrows;
  }
}

// ---------------------------------------------------------------------------
// K2: raw[i] = relu(x[i]@W1+b1)@W2+b2 via split-bf16 MFMA (3 products).
// 512 thr = 8 waves x 32 rows = 256 rows/block. W1-hi fragments staged once
// into 64 KB static LDS (shared by all 8 waves -> no per-wave L2 hi-stream);
// lo fragments stream from L2 (1 GB total, hidden under HBM x read).
// __launch_bounds__(512,4): 2 blocks/CU, VGPR<=128. Global max via per-wave
// encoded atomicMax (order-independent -> deterministic).
// ---------------------------------------------------------------------------
__global__ __launch_bounds__(512, 4)
void ap_mlp(const float* __restrict__ x, const unsigned short* __restrict__ w1hi,
            const unsigned short* __restrict__ w1lo, const float* __restrict__ b1,
            const float* __restrict__ W2, const float* __restrict__ b2,
            float* __restrict__ raw, unsigned* __restrict__ maxslot, int nrows) {
  __shared__ __align__(16) unsigned short shi[64 * 64 * 8];  // exactly 64 KB

  const int tid = threadIdx.x;
  const int wv = tid >> 6;
  const int l = tid & 63;
  const int l15 = l & 15, lhi = l >> 4;

  // stage W1-hi fragments: 4096 x 16B chunks, 512 threads x 8 iters
  {
    const f32x4* src = (const f32x4*)w1hi;
    f32x4* dst = (f32x4*)shi;
#pragma unroll
    for (int it = 0; it < 8; ++it) dst[it * 512 + tid] = src[it * 512 + tid];
  }
  __syncthreads();

  const long long base = (long long)blockIdx.x * 256 + wv * 32;
  long long r0 = base + l15;
  long long r1 = base + 16 + l15;
  if (r0 > (long long)nrows - 1) r0 = nrows - 1;
  if (r1 > (long long)nrows - 1) r1 = nrows - 1;
  const float* xr0 = x + r0 * DD + lhi * 8;
  const float* xr1 = x + r1 * DD + lhi * 8;

  f32x4 acc0[8], acc1[8];
#pragma unroll
  for (int nt = 0; nt < 8; ++nt) {
    acc0[nt] = f32x4{0.f, 0.f, 0.f, 0.f};
    acc1[nt] = f32x4{0.f, 0.f, 0.f, 0.f};
  }

#pragma unroll
  for (int kt = 0; kt < 8; ++kt) {
    const f32x4 u0 = *(const f32x4*)(xr0 + kt * 32);
    const f32x4 u1 = *(const f32x4*)(xr0 + kt * 32 + 4);
    const f32x4 v0 = *(const f32x4*)(xr1 + kt * 32);
    const f32x4 v1 = *(const f32x4*)(xr1 + kt * 32 + 4);
    bf16x8 ah0, al0, ah1, al1;
#pragma unroll
    for (int j = 0; j < 8; ++j) {
      const float f = (j < 4) ? u0[j] : u1[j - 4];
      const unsigned short h = f2bf_rne(f);
      ah0[j] = (short)h;
      al0[j] = (short)f2bf_rne(f - __uint_as_float((unsigned)h << 16));
      const float g = (j < 4) ? v0[j] : v1[j - 4];
      const unsigned short h2 = f2bf_rne(g);
      ah1[j] = (short)h2;
      al1[j] = (short)f2bf_rne(g - __uint_as_float((unsigned)h2 << 16));
    }
    const bf16x8* bh = (const bf16x8*)shi + (size_t)kt * 512;   // LDS
    const bf16x8* bl = (const bf16x8*)w1lo + (size_t)kt * 512;  // L2
#pragma unroll
    for (int nt = 0; nt < 8; ++nt) {
      const bf16x8 Bh = bh[nt * 64 + l];
      const bf16x8 Bl = bl[nt * 64 + l];
      acc0[nt] = __builtin_amdgcn_mfma_f32_16x16x32_bf16(ah0, Bh, acc0[nt], 0, 0, 0);
      acc0[nt] = __builtin_amdgcn_mfma_f32_16x16x32_bf16(al0, Bh, acc0[nt], 0, 0, 0);
      acc0[nt] = __builtin_amdgcn_mfma_f32_16x16x32_bf16(ah0, Bl, acc0[nt], 0, 0, 0);
      acc1[nt] = __builtin_amdgcn_mfma_f32_16x16x32_bf16(ah1, Bh, acc1[nt], 0, 0, 0);
      acc1[nt] = __builtin_amdgcn_mfma_f32_16x16x32_bf16(al1, Bh, acc1[nt], 0, 0, 0);
      acc1[nt] = __builtin_amdgcn_mfma_f32_16x16x32_bf16(ah1, Bl, acc1[nt], 0, 0, 0);
    }
  }

  // epilogue: relu + b1, dot W2 (b1/W2 loaded here to keep VGPR low),
  // reduce over the 16 col-lanes per cluster
  float pr0[4], pr1[4];
#pragma unroll
  for (int r = 0; r < 4; ++r) { pr0[r] = 0.f; pr1[r] = 0.f; }
#pragma unroll
  for (int nt = 0; nt < 8; ++nt) {
    const float b1f = b1[nt * 16 + l15];
    const float w2f = W2[nt * 16 + l15];
#pragma unroll
    for (int r = 0; r < 4; ++r) {
      pr0[r] += fmaxf(acc0[nt][r] + b1f, 0.f) * w2f;
      pr1[r] += fmaxf(acc1[nt][r] + b1f, 0.f) * w2f;
    }
  }
#pragma unroll
  for (int mm = 1; mm < 16; mm <<= 1) {
#pragma unroll
    for (int r = 0; r < 4; ++r) {
      pr0[r] += __shfl_xor(pr0[r], mm, 64);
      pr1[r] += __shfl_xor(pr1[r], mm, 64);
    }
  }
  const float bb = *b2;
  const long long w0row = base + lhi * 4;
  const long long w1row = base + 16 + lhi * 4;
  float mymax = -3.4e38f;
#pragma unroll
  for (int r = 0; r < 4; ++r) {
    const float s0 = pr0[r] + bb;
    const float s1 = pr1[r] + bb;
    if (w0row + r < (long long)nrows) {
      if (l15 == 0) raw[w0row + r] = s0;
      mymax = fmaxf(mymax, s0);
    }
    if (w1row + r < (long long)nrows) {
      if (l15 == 0) raw[w1row + r] = s1;
      mymax = fmaxf(mymax, s1);
    }
  }
  mymax = fmaxf(mymax, __shfl_xor(mymax, 16, 64));
  mymax = fmaxf(mymax, __shfl_xor(mymax, 32, 64));
  if (l == 0) atomicMax(maxslot, enc_f32(mymax));
}

// ---------------------------------------------------------------------------
// K3: block per segment, 512 thr (8 row-groups). Pass A: sum_w (fixed-order
// tree). Pass B: out[b] = (sum exp(raw-M)*x) / ((sum_w/cnt*N + 1e-8)*cnt).
// Deterministic: fixed-order reductions, no fp atomics.
// ---------------------------------------------------------------------------
__global__ __launch_bounds__(512)
void ap_pool(const float* __restrict__ x, const float* __restrict__ raw,
             const int* __restrict__ start, const unsigned* __restrict__ maxslot,
             float* __restrict__ out, int nrows) {
  __shared__ float sred[512];
  __shared__ f32x4 credp[8][64];
  const int b = blockIdx.x;
  const int s = start[b], e = start[b + 1];
  const int tid = threadIdx.x;
  const float M = dec_f32(*maxslot);

  // pass A: segment sum of w
  float a = 0.f;
  for (int i = s + tid; i < e; i += 512) a += expf(raw[i] - M);
  sred[tid] = a;
  __syncthreads();
  for (int off = 256; off > 0; off >>= 1) {
    if (tid < off) sred[tid] += sred[tid + off];
    __syncthreads();
  }
  const float sum = sred[0];
  const int cnt = e - s;
  const float cntf = (float)(cnt > 0 ? cnt : 1);
  const float scale = 1.0f / (((sum / cntf) * (float)nrows + 1e-8f) * cntf);

  // pass B: weighted row sum; wave rg handles rows == rg (mod 8), 2-deep
  const int dq = tid & 63;
  const int rg = tid >> 6;
  f32x4 acc = {0.f, 0.f, 0.f, 0.f};
  int i = s + rg;
  for (; i + 8 < e; i += 16) {
    const float wa = expf(raw[i] - M);
    const float wb = expf(raw[i + 8] - M);
    const f32x4 xa = *(const f32x4*)(x + (long long)i * DD + dq * 4);
    const f32x4 xb = *(const f32x4*)(x + (long long)(i + 8) * DD + dq * 4);
    acc += wa * xa + wb * xb;
  }
  if (i < e) {
    const float wa = expf(raw[i] - M);
    const f32x4 xa = *(const f32x4*)(x + (long long)i * DD + dq * 4);
    acc += wa * xa;
  }
  credp[rg][dq] = acc;
  __syncthreads();
  if (rg == 0) {
    f32x4 r = (((credp[0][dq] + credp[1][dq]) + (credp[2][dq] + credp[3][dq])) +
               ((credp[4][dq] + credp[5][dq]) + (credp[6][dq] + credp[7][dq])));
    r *= scale;
    *(f32x4*)(out + (long long)b * DD + dq * 4) = r;
  }
}

extern "C" void kernel_launch(void* const* d_in, const int* in_sizes, int n_in,
                              void* d_out, int out_size, void* d_ws, size_t ws_size,
                              hipStream_t stream) {
  const float* x     = (const float*)d_in[0];
  const int*   batch = (const int*)d_in[1];
  const float* W1    = (const float*)d_in[2];
  const float* b1    = (const float*)d_in[3];
  const float* W2    = (const float*)d_in[4];
  const float* b2    = (const float*)d_in[5];
  float* out = (float*)d_out;

  const int nrows = in_sizes[1];
  const int bseg = out_size / DD;

  // workspace layout (16B-aligned)
  unsigned short* w1hi = (unsigned short*)d_ws;              // 64 KB
  unsigned short* w1lo = w1hi + 64 * 64 * 8;                 // 64 KB
  float* raw = (float*)(w1lo + 64 * 64 * 8);                 // nrows fp32
  int* start = (int*)(raw + nrows);                          // bseg+1
  unsigned* maxslot = (unsigned*)(start + bseg + 1);         // 1

  ap_prep<<<16, 256, 0, stream>>>(W1, w1hi, w1lo, maxslot);
  ap_bounds<<<(nrows + 255) / 256, 256, 0, stream>>>(batch, start, nrows, bseg);
  ap_mlp<<<(nrows + 255) / 256, 512, 0, stream>>>(x, w1hi, w1lo, b1, W2, b2, raw,
                                                  maxslot, nrows);
  ap_pool<<<bseg, 512, 0, stream>>>(x, raw, start, maxslot, out, nrows);
}

// Round 6
// 319.935 us; speedup vs baseline: 1.1239x; 1.1239x over previous
//
#include <hip/hip_runtime.h>
#include <math.h>

typedef float f32x4 __attribute__((ext_vector_type(4)));
typedef __attribute__((ext_vector_type(8))) _Float16 f16x8;

#define DD 256
#define DH 128

// order-preserving float<->uint encoding for deterministic atomicMax
__device__ __forceinline__ unsigned enc_f32(float f) {
  unsigned u = __float_as_uint(f);
  return (u & 0x80000000u) ? ~u : (u | 0x80000000u);
}
__device__ __forceinline__ float dec_f32(unsigned u) {
  return __uint_as_float((u & 0x80000000u) ? (u ^ 0x80000000u) : ~u);
}

// ---------------------------------------------------------------------------
// K0: W1 (256x128 fp32) -> f16 MFMA B-fragment order (single product, the
// dropped x*W_lo term is ~2^-11 relative -> ~1e-9 abs on out, ~10x margin).
// w1f[((kt*8+nt)*64+l)*8+j] = f16(W1[kt*32+(l>>4)*8+j][nt*16+(l&15)])
// Also initializes maxslot (runs before ap_mlp on the same stream).
// ---------------------------------------------------------------------------
__global__ void ap_prep(const float* __restrict__ W1,
                        _Float16* __restrict__ w1f,
                        unsigned* __restrict__ maxslot) {
  int t = blockIdx.x * blockDim.x + threadIdx.x;  // 0..4095
  if (t == 0) *maxslot = 0u;
  if (t >= 64 * 64) return;
  int l = t & 63;
  int tile = t >> 6;  // kt*8 + nt
  int kt = tile >> 3, nt = tile & 7;
  int kbase = kt * 32 + (l >> 4) * 8;
  int col = nt * 16 + (l & 15);
#pragma unroll
  for (int j = 0; j < 8; ++j) {
    w1f[t * 8 + j] = (_Float16)W1[(kbase + j) * DH + col];
  }
}

// ---------------------------------------------------------------------------
// K1: segment boundaries (batch sorted). start[b] = first i with batch[i]>=b
// ---------------------------------------------------------------------------
__global__ void ap_bounds(const int* __restrict__ batch, int* __restrict__ start,
                          int nrows, int bseg) {
  int i = blockIdx.x * blockDim.x + threadIdx.x;
  if (i >= nrows) return;
  int c = batch[i];
  int p = (i == 0) ? -1 : batch[i - 1];
  for (int b = p + 1; b <= c; ++b) start[b] = i;
  if (i == nrows - 1) {
    for (int b = c + 1; b <= bseg; ++b) start[b] = nrows;
  }
}

// ---------------------------------------------------------------------------
// K2: raw[i] = relu(x[i]@W1+b1)@W2+b2 via split-f16 MFMA (2 products:
// (xh + xl) @ W_f16). B (64 KB) lives entirely in LDS -> zero L2 B-stream.
// 512 thr = 8 waves x 32 rows = 256 rows/block; 2 blocks/CU (LDS), VGPR<=128
// with rolled kt-loop (no spill). Global max via per-wave encoded atomicMax.
// ---------------------------------------------------------------------------
__global__ __launch_bounds__(512, 4)
void ap_mlp(const float* __restrict__ x, const _Float16* __restrict__ w1f,
            const float* __restrict__ b1, const float* __restrict__ W2,
            const float* __restrict__ b2, float* __restrict__ raw,
            unsigned* __restrict__ maxslot, int nrows) {
  __shared__ __align__(16) _Float16 sB[64 * 64 * 8];  // exactly 64 KB

  const int tid = threadIdx.x;
  const int wv = tid >> 6;
  const int l = tid & 63;
  const int l15 = l & 15, lhi = l >> 4;

  // stage B fragments: 4096 x 16B chunks, 512 threads x 8 iters
  {
    const f32x4* src = (const f32x4*)w1f;
    f32x4* dst = (f32x4*)sB;
#pragma unroll
    for (int it = 0; it < 8; ++it) dst[it * 512 + tid] = src[it * 512 + tid];
  }
  __syncthreads();

  const long long base = (long long)blockIdx.x * 256 + wv * 32;
  long long r0 = base + l15;
  long long r1 = base + 16 + l15;
  if (r0 > (long long)nrows - 1) r0 = nrows - 1;
  if (r1 > (long long)nrows - 1) r1 = nrows - 1;
  const float* xr0 = x + r0 * DD + lhi * 8;
  const float* xr1 = x + r1 * DD + lhi * 8;

  f32x4 acc0[8], acc1[8];
#pragma unroll
  for (int nt = 0; nt < 8; ++nt) {
    acc0[nt] = f32x4{0.f, 0.f, 0.f, 0.f};
    acc1[nt] = f32x4{0.f, 0.f, 0.f, 0.f};
  }

#pragma unroll 1
  for (int kt = 0; kt < 8; ++kt) {
    const f32x4 u0 = *(const f32x4*)(xr0 + kt * 32);
    const f32x4 u1 = *(const f32x4*)(xr0 + kt * 32 + 4);
    const f32x4 v0 = *(const f32x4*)(xr1 + kt * 32);
    const f32x4 v1 = *(const f32x4*)(xr1 + kt * 32 + 4);
    f16x8 ah0, al0, ah1, al1;
#pragma unroll
    for (int j = 0; j < 8; ++j) {
      const float f = (j < 4) ? u0[j] : u1[j - 4];
      const _Float16 h = (_Float16)f;
      ah0[j] = h;
      al0[j] = (_Float16)(f - (float)h);
      const float g = (j < 4) ? v0[j] : v1[j - 4];
      const _Float16 h2 = (_Float16)g;
      ah1[j] = h2;
      al1[j] = (_Float16)(g - (float)h2);
    }
    const f16x8* bh = (const f16x8*)sB + (size_t)kt * 512;  // LDS
#pragma unroll
    for (int nt = 0; nt < 8; ++nt) {
      const f16x8 Bh = bh[nt * 64 + l];
      acc0[nt] = __builtin_amdgcn_mfma_f32_16x16x32_f16(ah0, Bh, acc0[nt], 0, 0, 0);
      acc0[nt] = __builtin_amdgcn_mfma_f32_16x16x32_f16(al0, Bh, acc0[nt], 0, 0, 0);
      acc1[nt] = __builtin_amdgcn_mfma_f32_16x16x32_f16(ah1, Bh, acc1[nt], 0, 0, 0);
      acc1[nt] = __builtin_amdgcn_mfma_f32_16x16x32_f16(al1, Bh, acc1[nt], 0, 0, 0);
    }
  }

  // epilogue: relu + b1, dot W2 (loaded here to keep VGPR low),
  // reduce over the 16 col-lanes per cluster
  float pr0[4], pr1[4];
#pragma unroll
  for (int r = 0; r < 4; ++r) { pr0[r] = 0.f; pr1[r] = 0.f; }
#pragma unroll
  for (int nt = 0; nt < 8; ++nt) {
    const float b1f = b1[nt * 16 + l15];
    const float w2f = W2[nt * 16 + l15];
#pragma unroll
    for (int r = 0; r < 4; ++r) {
      pr0[r] += fmaxf(acc0[nt][r] + b1f, 0.f) * w2f;
      pr1[r] += fmaxf(acc1[nt][r] + b1f, 0.f) * w2f;
    }
  }
#pragma unroll
  for (int mm = 1; mm < 16; mm <<= 1) {
#pragma unroll
    for (int r = 0; r < 4; ++r) {
      pr0[r] += __shfl_xor(pr0[r], mm, 64);
      pr1[r] += __shfl_xor(pr1[r], mm, 64);
    }
  }
  const float bb = *b2;
  const long long w0row = base + lhi * 4;
  const long long w1row = base + 16 + lhi * 4;
  float mymax = -3.4e38f;
#pragma unroll
  for (int r = 0; r < 4; ++r) {
    const float s0 = pr0[r] + bb;
    const float s1 = pr1[r] + bb;
    if (w0row + r < (long long)nrows) {
      if (l15 == 0) raw[w0row + r] = s0;
      mymax = fmaxf(mymax, s0);
    }
    if (w1row + r < (long long)nrows) {
      if (l15 == 0) raw[w1row + r] = s1;
      mymax = fmaxf(mymax, s1);
    }
  }
  mymax = fmaxf(mymax, __shfl_xor(mymax, 16, 64));
  mymax = fmaxf(mymax, __shfl_xor(mymax, 32, 64));
  if (l == 0) atomicMax(maxslot, enc_f32(mymax));
}

// ---------------------------------------------------------------------------
// K3: block per segment, 512 thr (8 row-groups). Pass A: sum_w (fixed-order
// tree). Pass B: out[b] = (sum exp(raw-M)*x) / ((sum_w/cnt*N + 1e-8)*cnt).
// Deterministic: fixed-order reductions, no fp atomics.
// ---------------------------------------------------------------------------
__global__ __launch_bounds__(512)
void ap_pool(const float* __restrict__ x, const float* __restrict__ raw,
             const int* __restrict__ start, const unsigned* __restrict__ maxslot,
             float* __restrict__ out, int nrows) {
  __shared__ float sred[512];
  __shared__ f32x4 credp[8][64];
  const int b = blockIdx.x;
  const int s = start[b], e = start[b + 1];
  const int tid = threadIdx.x;
  const float M = dec_f32(*maxslot);

  // pass A: segment sum of w
  float a = 0.f;
  for (int i = s + tid; i < e; i += 512) a += expf(raw[i] - M);
  sred[tid] = a;
  __syncthreads();
  for (int off = 256; off > 0; off >>= 1) {
    if (tid < off) sred[tid] += sred[tid + off];
    __syncthreads();
  }
  const float sum = sred[0];
  const int cnt = e - s;
  const float cntf = (float)(cnt > 0 ? cnt : 1);
  const float scale = 1.0f / (((sum / cntf) * (float)nrows + 1e-8f) * cntf);

  // pass B: weighted row sum; wave rg handles rows == rg (mod 8), 2-deep
  const int dq = tid & 63;
  const int rg = tid >> 6;
  f32x4 acc = {0.f, 0.f, 0.f, 0.f};
  int i = s + rg;
  for (; i + 8 < e; i += 16) {
    const float wa = expf(raw[i] - M);
    const float wb = expf(raw[i + 8] - M);
    const f32x4 xa = *(const f32x4*)(x + (long long)i * DD + dq * 4);
    const f32x4 xb = *(const f32x4*)(x + (long long)(i + 8) * DD + dq * 4);
    acc += wa * xa + wb * xb;
  }
  if (i < e) {
    const float wa = expf(raw[i] - M);
    const f32x4 xa = *(const f32x4*)(x + (long long)i * DD + dq * 4);
    acc += wa * xa;
  }
  credp[rg][dq] = acc;
  __syncthreads();
  if (rg == 0) {
    f32x4 r = (((credp[0][dq] + credp[1][dq]) + (credp[2][dq] + credp[3][dq])) +
               ((credp[4][dq] + credp[5][dq]) + (credp[6][dq] + credp[7][dq])));
    r *= scale;
    *(f32x4*)(out + (long long)b * DD + dq * 4) = r;
  }
}

extern "C" void kernel_launch(void* const* d_in, const int* in_sizes, int n_in,
                              void* d_out, int out_size, void* d_ws, size_t ws_size,
                              hipStream_t stream) {
  const float* x     = (const float*)d_in[0];
  const int*   batch = (const int*)d_in[1];
  const float* W1    = (const float*)d_in[2];
  const float* b1    = (const float*)d_in[3];
  const float* W2    = (const float*)d_in[4];
  const float* b2    = (const float*)d_in[5];
  float* out = (float*)d_out;

  const int nrows = in_sizes[1];
  const int bseg = out_size / DD;

  // workspace layout (16B-aligned)
  _Float16* w1f = (_Float16*)d_ws;                           // 64 KB
  float* raw = (float*)(w1f + 64 * 64 * 8);                  // nrows fp32
  int* start = (int*)(raw + nrows);                          // bseg+1
  unsigned* maxslot = (unsigned*)(start + bseg + 1);         // 1

  ap_prep<<<16, 256, 0, stream>>>(W1, w1f, maxslot);
  ap_bounds<<<(nrows + 255) / 256, 256, 0, stream>>>(batch, start, nrows, bseg);
  ap_mlp<<<(nrows + 255) / 256, 512, 0, stream>>>(x, w1f, b1, W2, b2, raw,
                                                  maxslot, nrows);
  ap_pool<<<bseg, 512, 0, stream>>>(x, raw, start, maxslot, out, nrows);
}

// Round 7
// 297.079 us; speedup vs baseline: 1.2104x; 1.0769x over previous
//
#include <hip/hip_runtime.h>
#include <math.h>

typedef float f32x4 __attribute__((ext_vector_type(4)));
typedef __attribute__((ext_vector_type(8))) _Float16 f16x8;

#define DD 256
#define DH 128

// ---------------------------------------------------------------------------
// K0: W1 (256x128 fp32) -> f16 MFMA B-fragment order.
// w1f[((kt*8+nt)*64+l)*8+j] = f16(W1[kt*32+(l>>4)*8+j][nt*16+(l&15)])
// ---------------------------------------------------------------------------
__global__ void ap_prep(const float* __restrict__ W1, _Float16* __restrict__ w1f) {
  int t = blockIdx.x * blockDim.x + threadIdx.x;  // 0..4095
  if (t >= 64 * 64) return;
  int l = t & 63;
  int tile = t >> 6;  // kt*8 + nt
  int kt = tile >> 3, nt = tile & 7;
  int kbase = kt * 32 + (l >> 4) * 8;
  int col = nt * 16 + (l & 15);
#pragma unroll
  for (int j = 0; j < 8; ++j) {
    w1f[t * 8 + j] = (_Float16)W1[(kbase + j) * DH + col];
  }
}

// ---------------------------------------------------------------------------
// K1: segment boundaries (batch sorted). start[b] = first i with batch[i]>=b
// ---------------------------------------------------------------------------
__global__ void ap_bounds(const int* __restrict__ batch, int* __restrict__ start,
                          int nrows, int bseg) {
  int i = blockIdx.x * blockDim.x + threadIdx.x;
  if (i >= nrows) return;
  int c = batch[i];
  int p = (i == 0) ? -1 : batch[i - 1];
  for (int b = p + 1; b <= c; ++b) start[b] = i;
  if (i == nrows - 1) {
    for (int b = c + 1; b <= bseg; ++b) start[b] = nrows;
  }
}

// ---------------------------------------------------------------------------
// K2: fully fused, block per segment, single x read.
// Per 128-row tile (8 waves x 16 rows): wave loads its 16 rows into regs
// (16 f32x4/lane), split-f16 MFMA vs LDS-resident B -> raw; per-segment
// online max; pooling reuses the SAME x registers (butterfly over the 16
// row-lanes) into per-wave LDS accumulators. Deterministic: one block per
// segment, fixed-order reductions, no fp atomics. Global max dropped:
// it cancels except in the 1e-8 term (rel ~7e-13, far under threshold).
// ---------------------------------------------------------------------------
__global__ __launch_bounds__(512)
void ap_fused(const float* __restrict__ x, const _Float16* __restrict__ w1f,
              const float* __restrict__ b1, const float* __restrict__ W2,
              const float* __restrict__ b2, const int* __restrict__ start,
              float* __restrict__ out, int nrows) {
  __shared__ __align__(16) _Float16 sB[64 * 64 * 8];  // 64 KB B fragments
  __shared__ float rawp[128];                         // raw for tile rows
  __shared__ __align__(16) float pooled[8][256];      // per-wave pooled acc
  __shared__ float swarr[8];

  const int tid = threadIdx.x;
  const int wv = tid >> 6;
  const int l = tid & 63;
  const int l15 = l & 15, lhi = l >> 4;
  const int b = blockIdx.x;
  const int s = start[b], e = start[b + 1];

  // stage B fragments: 4096 x 16B chunks
  {
    const f32x4* src = (const f32x4*)w1f;
    f32x4* dst = (f32x4*)sB;
#pragma unroll
    for (int it = 0; it < 8; ++it) dst[it * 512 + tid] = src[it * 512 + tid];
  }
  ((f32x4*)pooled)[tid] = f32x4{0.f, 0.f, 0.f, 0.f};  // 512 chunks = 8x256 f32
  __syncthreads();

  float b1f[8], w2f[8];
#pragma unroll
  for (int nt = 0; nt < 8; ++nt) {
    b1f[nt] = b1[nt * 16 + l15];
    w2f[nt] = W2[nt * 16 + l15];
  }
  const float bb = *b2;

  float m = -__builtin_inff();
  float swv = 0.f;

  for (int t0 = s; t0 < e; t0 += 128) {
    // ---- load this wave's 16 rows into registers (row l15, cols lhi*8+kt*32)
    const int row = t0 + wv * 16 + l15;
    const long long rowc = (row < e) ? row : (e - 1);
    const float* xr = x + rowc * DD + lhi * 8;
    f32x4 xv[16];
#pragma unroll
    for (int kt = 0; kt < 8; ++kt) {
      xv[2 * kt] = *(const f32x4*)(xr + kt * 32);
      xv[2 * kt + 1] = *(const f32x4*)(xr + kt * 32 + 4);
    }

    // ---- MLP: split-f16 MFMA over all 8 nt (B from LDS) ----
    f32x4 acc[8];
#pragma unroll
    for (int nt = 0; nt < 8; ++nt) acc[nt] = f32x4{0.f, 0.f, 0.f, 0.f};
#pragma unroll
    for (int kt = 0; kt < 8; ++kt) {
      f16x8 ah, al;
#pragma unroll
      for (int j = 0; j < 8; ++j) {
        const float f = (j < 4) ? xv[2 * kt][j] : xv[2 * kt + 1][j - 4];
        const _Float16 h = (_Float16)f;
        ah[j] = h;
        al[j] = (_Float16)(f - (float)h);
      }
      const f16x8* bh = (const f16x8*)sB + (size_t)kt * 512;
#pragma unroll
      for (int nt = 0; nt < 8; ++nt) {
        const f16x8 Bh = bh[nt * 64 + l];
        acc[nt] = __builtin_amdgcn_mfma_f32_16x16x32_f16(ah, Bh, acc[nt], 0, 0, 0);
        acc[nt] = __builtin_amdgcn_mfma_f32_16x16x32_f16(al, Bh, acc[nt], 0, 0, 0);
      }
    }

    // ---- epilogue: relu+b1, dot W2, reduce over 16 col-lanes -> rawp ----
    float pr[4];
#pragma unroll
    for (int r = 0; r < 4; ++r) pr[r] = 0.f;
#pragma unroll
    for (int nt = 0; nt < 8; ++nt) {
#pragma unroll
      for (int r = 0; r < 4; ++r)
        pr[r] += fmaxf(acc[nt][r] + b1f[nt], 0.f) * w2f[nt];
    }
#pragma unroll
    for (int mm = 1; mm < 16; mm <<= 1) {
#pragma unroll
      for (int r = 0; r < 4; ++r) pr[r] += __shfl_xor(pr[r], mm, 64);
    }
    if (l15 == 0) {
      const int wr0 = t0 + wv * 16 + lhi * 4;
#pragma unroll
      for (int r = 0; r < 4; ++r) {
        rawp[wv * 16 + lhi * 4 + r] =
            (wr0 + r < e) ? (pr[r] + bb) : -__builtin_inff();
      }
    }
    __syncthreads();

    // ---- online-softmax update (redundant per thread; identical) ----
    float tv = fmaxf(rawp[l], rawp[64 + l]);
#pragma unroll
    for (int mm = 1; mm < 64; mm <<= 1) tv = fmaxf(tv, __shfl_xor(tv, mm, 64));
    const float mn = fmaxf(m, tv);          // finite: row t0 always valid
    const float factor = expf(m - mn);      // first tile: exp(-inf)=0
    m = mn;

    // w for this lane's pooling row (== its x-register row, l15)
    const float wrow = expf(rawp[wv * 16 + l15] - m);  // invalid row -> 0
    float ws_ = wrow;
#pragma unroll
    for (int mm = 1; mm < 16; mm <<= 1) ws_ += __shfl_xor(ws_, mm, 64);
    swv = swv * factor + ws_;

    // ---- pooling: xv *= w, butterfly-sum over the 16 row-lanes ----
#pragma unroll
    for (int j = 0; j < 16; ++j) xv[j] *= wrow;
#pragma unroll
    for (int mm = 1; mm < 16; mm <<= 1) {
#pragma unroll
      for (int j = 0; j < 16; ++j) {
        f32x4 o;
        o[0] = __shfl_xor(xv[j][0], mm, 64);
        o[1] = __shfl_xor(xv[j][1], mm, 64);
        o[2] = __shfl_xor(xv[j][2], mm, 64);
        o[3] = __shfl_xor(xv[j][3], mm, 64);
        xv[j] += o;
      }
    }
    // accumulate into this wave's pooled slot (static reg indices; l15==0
    // lanes of each lhi group write their 16 col-chunks, rescaled by factor)
    if (l15 == 0) {
      f32x4* pw = (f32x4*)pooled[wv];
#pragma unroll
      for (int j = 0; j < 16; ++j) {
        const int c = lhi * 2 + (j >> 1) * 8 + (j & 1);
        pw[c] = pw[c] * factor + xv[j];
      }
    }
    __syncthreads();  // rawp consumed; next tile may overwrite
  }

  // ---- finalize: combine 8 wave slots + sum_w, scale, write out ----
  if (l == 0) swarr[wv] = swv;
  __syncthreads();
  float sum_w = 0.f;
#pragma unroll
  for (int q = 0; q < 8; ++q) sum_w += swarr[q];
  const int cnt = e - s;
  const float cntf = (float)(cnt > 0 ? cnt : 1);
  const float scale = 1.0f / (((sum_w / cntf) * (float)nrows + 1e-8f) * cntf);
  if (tid < 64) {
    f32x4 v = (((f32x4*)pooled[0])[tid] + ((f32x4*)pooled[1])[tid]) +
              (((f32x4*)pooled[2])[tid] + ((f32x4*)pooled[3])[tid]);
    f32x4 w = (((f32x4*)pooled[4])[tid] + ((f32x4*)pooled[5])[tid]) +
              (((f32x4*)pooled[6])[tid] + ((f32x4*)pooled[7])[tid]);
    f32x4 r = (v + w) * scale;
    *(f32x4*)(out + (size_t)b * DD + tid * 4) = r;
  }
}

extern "C" void kernel_launch(void* const* d_in, const int* in_sizes, int n_in,
                              void* d_out, int out_size, void* d_ws, size_t ws_size,
                              hipStream_t stream) {
  const float* x     = (const float*)d_in[0];
  const int*   batch = (const int*)d_in[1];
  const float* W1    = (const float*)d_in[2];
  const float* b1    = (const float*)d_in[3];
  const float* W2    = (const float*)d_in[4];
  const float* b2    = (const float*)d_in[5];
  float* out = (float*)d_out;

  const int nrows = in_sizes[1];
  const int bseg = out_size / DD;

  // workspace layout (16B-aligned)
  _Float16* w1f = (_Float16*)d_ws;                  // 64 KB
  int* start = (int*)(w1f + 64 * 64 * 8);           // bseg+1

  ap_prep<<<16, 256, 0, stream>>>(W1, w1f);
  ap_bounds<<<(nrows + 255) / 256, 256, 0, stream>>>(batch, start, nrows, bseg);
  ap_fused<<<bseg, 512, 0, stream>>>(x, w1f, b1, W2, b2, start, out, nrows);
}